// Round 15
// baseline (111.968 us; speedup 1.0000x reference)
//
#include <hip/hip_runtime.h>

// SEIR SDE: B=32768 x 1000 steps -> out[step][4][B] f32 = 524 MB (write-bound).
// Ladder: 242 -> 115.6 -> 97.2 (R7) -> 94.2 (R12). Falsified: barrier drain
// (R8), compute-LDS (R11), prefetch (R3), store width 3-way w/ guards (R13),
// XCD swizzle (R14). Key unexploited datum: R10 measured compute at ILP=2 =
// 144 cyc per 64-traj step (vs 233 at ILP=1); R11->R12 showed drain was
// binding ~247 -> system sits at fill~drain~226. R15 drops BOTH below the
// 183 cyc/step HBM floor: 256 blocks (1/CU, enforced by 96KB LDS), block =
// 1 compute wave @ ILP=2 (128 trajs) + 2 store waves split BY COMPONENT PAIR
// (identical K=20 loops, no guards; 1KB contiguous ds_read_b128 + dwordx4 =
// 2x512B segments; R12 va/vb double register sets for stores-in-flight).

constexpr int   B_TRAJ  = 32768;
constexpr int   NSTEPS  = 1000;
constexpr int   K       = 20;            // steps per chunk
constexpr int   NC      = NSTEPS / K;    // 50 chunks (even)
constexpr int   TPB     = 128;           // trajectories per block
constexpr float DT      = 0.01f;
constexpr float EPS     = 1e-6f;
constexpr float INV_N   = 1.0f / 10000.0f;

// Barrier without vmcnt drain: LDS ordering only; global stores stay in
// flight across chunk boundaries.
__device__ __forceinline__ void barrier_lds_only() {
    asm volatile("s_waitcnt lgkmcnt(0)" ::: "memory");
    __builtin_amdgcn_s_barrier();
    asm volatile("" ::: "memory");
}

__global__ __launch_bounds__(192) void seir_sde_kernel(
    const float* __restrict__ beta,
    const float* __restrict__ sigma,
    const float* __restrict__ gamma,
    const float* __restrict__ S0,
    const float* __restrict__ E0,
    const float* __restrict__ I0,
    const float* __restrict__ R0,
    const float4* __restrict__ dW,   // [NSTEPS] raw (w0,w1,w2,w3)
    float* __restrict__ out)         // [NSTEPS][4][B_TRAJ]
{
    __shared__ float4 wbuf[NSTEPS];          // pre-scaled noise, 16 KB
    __shared__ float  ring[2][K][4][TPB];    // SoA chunk ring, 80 KB
                                             // total 96 KB -> HW caps 1 block/CU

    // Folded constants (3 scalar loads, once, all threads).
    const float btnD = beta[0] * INV_N * DT; // (beta/N)*DT
    const float sgD  = sigma[0] * DT;        // sigma*DT
    const float gmD  = gamma[0] * DT;        // gamma*DT
    const float sbi  = __builtin_amdgcn_sqrtf(btnD);
    const float sbe  = __builtin_amdgcn_sqrtf(sgD);
    const float sbr  = __builtin_amdgcn_sqrtf(gmD);

    // Stage noise pre-multiplied: per-step diffusion becomes sqrt(P)*w.
    for (int i = threadIdx.x; i < NSTEPS; i += 192) {
        const float4 w = dW[i];
        wbuf[i] = make_float4(w.x * sbi, w.y * sbe, w.z * sbr, 0.0f);
    }

    const int lane = threadIdx.x & 63;
    const int wid  = threadIdx.x >> 6;       // 0 = compute; 1,2 = store waves

    // Compute wave: thread 'lane' owns trajectories base, base+1 (ILP=2).
    float Sa=0.f,Ea=0.f,Ia=0.f,Ra=0.f, Sb=0.f,Eb=0.f,Ib=0.f,Rb=0.f;
    if (wid == 0) {
        const int a = blockIdx.x * TPB + 2 * lane;
        const float2 s2 = *(const float2*)&S0[a];
        const float2 e2 = *(const float2*)&E0[a];
        const float2 i2 = *(const float2*)&I0[a];
        const float2 r2 = *(const float2*)&R0[a];
        Sa = s2.x; Sb = s2.y; Ea = e2.x; Eb = e2.y;
        Ia = i2.x; Ib = i2.y; Ra = r2.x; Rb = r2.y;
    }

    // Store wave j (wid-1): components c0=2j, c0+1. Lanes 0-31 -> comp c0,
    // lanes 32-63 -> comp c0+1; each half writes a contiguous 512B segment.
    const int c0 = (wid - 1) * 2;            // valid for wid>=1
    float* const obase = out + blockIdx.x * TPB
                             + (c0 + (lane >> 5)) * B_TRAJ + (lane & 31) * 4;

    // One ILP=2 SEIR step (two independent chains fill each other's bubbles).
    // Algebra verbatim R12 (validated absmax 0.0): diffusion = sqrt(P)*w with
    // sqrt(rate-const*DT) folded into wbuf at staging.
    #define SEIR2(w, dst)                                                      \
    {                                                                          \
        const float Sc0=fmaxf(Sa,EPS), Ec0=fmaxf(Ea,EPS);                      \
        const float Ic0=fmaxf(Ia,EPS), Rc0=fmaxf(Ra,EPS);                      \
        const float Sc1=fmaxf(Sb,EPS), Ec1=fmaxf(Eb,EPS);                      \
        const float Ic1=fmaxf(Ib,EPS), Rc1=fmaxf(Rb,EPS);                      \
        const float P0=Sc0*Ic0, P1=Sc1*Ic1;                                    \
        const float iD0=btnD*P0, eD0=sgD*Ec0, rD0=gmD*Ic0;                     \
        const float iD1=btnD*P1, eD1=sgD*Ec1, rD1=gmD*Ic1;                     \
        const float ai0=__builtin_amdgcn_sqrtf(P0) *(w).x;                     \
        const float ae0=__builtin_amdgcn_sqrtf(Ec0)*(w).y;                     \
        const float ar0=__builtin_amdgcn_sqrtf(Ic0)*(w).z;                     \
        const float ai1=__builtin_amdgcn_sqrtf(P1) *(w).x;                     \
        const float ae1=__builtin_amdgcn_sqrtf(Ec1)*(w).y;                     \
        const float ar1=__builtin_amdgcn_sqrtf(Ic1)*(w).z;                     \
        const float Sn0=Sc0-iD0-ai0,  En0=Ec0+iD0-eD0+ai0-ae0;                 \
        const float In0=Ic0+eD0-rD0+ae0-ar0, Rn0=Rc0+rD0+ar0;                  \
        const float Sn1=Sc1-iD1-ai1,  En1=Ec1+iD1-eD1+ai1-ae1;                 \
        const float In1=Ic1+eD1-rD1+ae1-ar1, Rn1=Rc1+rD1+ar1;                  \
        *(float2*)&(dst)[0][2*lane] = make_float2(Sn0, Sn1);                   \
        *(float2*)&(dst)[1][2*lane] = make_float2(En0, En1);                   \
        *(float2*)&(dst)[2][2*lane] = make_float2(In0, In1);                   \
        *(float2*)&(dst)[3][2*lane] = make_float2(Rn0, Rn1);                   \
        Sa=Sn0; Ea=En0; Ia=In0; Ra=Rn0;                                        \
        Sb=Sn1; Eb=En1; Ib=In1; Rb=Rn1;                                        \
    }

    // Compute wave: fill chunk c into ring[c&1].
    #define FILL(c)                                                            \
    {                                                                          \
        const int s0 = (c) * K;                                                \
        float (*rw)[4][TPB] = ring[(c) & 1];                                   \
        _Pragma("unroll")                                                      \
        for (int k = 0; k < K; ++k) {                                          \
            const float4 w = wbuf[s0 + k];                                     \
            SEIR2(w, rw[k]);                                                   \
        }                                                                      \
    }

    // Store wave: drain its comp-pair slice of chunk c via register set v.
    // Per step: one contiguous 1KB ds_read_b128 + one dwordx4 (2x512B segs).
    // Alternating v sets across chunks => WAR wait is a counted vmcnt,
    // keeping a full chunk-slice of stores in flight permanently.
    #define STORE_CHUNK(c, v)                                                  \
    {                                                                          \
        const float4* rd = (const float4*)&ring[(c) & 1][0][c0][0];            \
        float* o = obase + (size_t)((c) * K) * (4 * B_TRAJ);                   \
        _Pragma("unroll")                                                      \
        for (int k = 0; k < K; ++k) v[k] = rd[k * (4 * TPB / 4) + lane];       \
        _Pragma("unroll")                                                      \
        for (int k = 0; k < K; ++k) {                                          \
            *(float4*)o = v[k];                                                \
            o += 4 * B_TRAJ;                                                   \
        }                                                                      \
    }

    float4 va[K], vb[K];                     // two in-flight store sets

    __syncthreads();                         // noise staged (once; drain ok)

    // ---- prologue: compute wave fills chunk 0 ----
    if (wid == 0) FILL(0);
    barrier_lds_only();

    // ---- pipeline, 2 chunks per iteration (NC even) ----
    for (int cc = 0; cc < NC; cc += 2) {
        if (wid == 0) { FILL(cc + 1); }
        else          { STORE_CHUNK(cc, va); }
        barrier_lds_only();
        if (wid == 0) { if (cc + 2 < NC) FILL(cc + 2); }
        else          { STORE_CHUNK(cc + 1, vb); }
        barrier_lds_only();
    }
    #undef SEIR2
    #undef FILL
    #undef STORE_CHUNK
}

extern "C" void kernel_launch(void* const* d_in, const int* in_sizes, int n_in,
                              void* d_out, int out_size, void* d_ws, size_t ws_size,
                              hipStream_t stream) {
    const float*  beta  = (const float*)d_in[0];
    const float*  sigma = (const float*)d_in[1];
    const float*  gamma = (const float*)d_in[2];
    const float*  S0    = (const float*)d_in[3];
    const float*  E0    = (const float*)d_in[4];
    const float*  I0    = (const float*)d_in[5];
    const float*  R0    = (const float*)d_in[6];
    const float4* dW    = (const float4*)d_in[7];
    float* out = (float*)d_out;

    seir_sde_kernel<<<B_TRAJ / TPB, 192, 0, stream>>>(
        beta, sigma, gamma, S0, E0, I0, R0, dW, out);
}

// Round 16
// 109.291 us; speedup vs baseline: 1.0245x; 1.0245x over previous
//
#include <hip/hip_runtime.h>

// SEIR SDE: B=32768 x 1000 steps -> out[step][4][B] f32 = 524 MB (write-bound).
// Ladder: 242 -> 115.6 -> 97.2 (R7) -> 94.2 (R12). R15 (ILP=2 single compute
// wave/CU) regressed: two parallel 64-traj compute waves/CU (R12) beat one
// 128-traj wave. R12 accounting: chunk 4522 cyc ~= fill 4660 (233 cyc/step)
// > drain 3660 -> FILL-limited. 233 = issue ~78 + chain ~45 + ~110 unexplained
// ~= single-outstanding ds_read_b128 noise latency per step (R11's hoist was
// confounded by a bad store-side change; combo untested until now).
// R16 = R12 + (a) per-chunk noise hoist into registers (wv[20], static-indexed
// after full unroll), (b) fma-fused algebra: u=fma(btnD,P,sqrt(P)*wx) etc.,
// 23->15 VALU/step. Identical topology/store machinery to R12.

constexpr int   B_TRAJ  = 32768;
constexpr int   NSTEPS  = 1000;
constexpr int   K       = 20;            // steps per chunk
constexpr int   NC      = NSTEPS / K;    // 50 chunks (even)
constexpr float DT      = 0.01f;
constexpr float EPS     = 1e-6f;
constexpr float INV_N   = 1.0f / 10000.0f;

// Barrier without vmcnt drain: LDS ordering only; global stores stay in
// flight across chunk boundaries.
__device__ __forceinline__ void barrier_lds_only() {
    asm volatile("s_waitcnt lgkmcnt(0)" ::: "memory");
    __builtin_amdgcn_s_barrier();
    asm volatile("" ::: "memory");
}

__global__ __launch_bounds__(128) void seir_sde_kernel(
    const float* __restrict__ beta,
    const float* __restrict__ sigma,
    const float* __restrict__ gamma,
    const float* __restrict__ S0,
    const float* __restrict__ E0,
    const float* __restrict__ I0,
    const float* __restrict__ R0,
    const float4* __restrict__ dW,   // [NSTEPS] raw (w0,w1,w2,w3)
    float* __restrict__ out)         // [NSTEPS][4][B_TRAJ]
{
    __shared__ float4 wbuf[NSTEPS];          // pre-scaled noise, 16 KB
    __shared__ float  ring[2][K][4][64];     // SoA chunk ring, 40 KB

    // Folded constants (3 scalar loads, once, all threads).
    const float btnD = beta[0] * INV_N * DT; // (beta/N)*DT
    const float sgD  = sigma[0] * DT;        // sigma*DT
    const float gmD  = gamma[0] * DT;        // gamma*DT
    const float sbi  = __builtin_amdgcn_sqrtf(btnD);
    const float sbe  = __builtin_amdgcn_sqrtf(sgD);
    const float sbr  = __builtin_amdgcn_sqrtf(gmD);

    // Stage noise pre-multiplied: per-step diffusion becomes sqrt(P)*w.
    for (int i = threadIdx.x; i < NSTEPS; i += 128) {
        const float4 w = dW[i];
        wbuf[i] = make_float4(w.x * sbi, w.y * sbe, w.z * sbr, 0.0f);
    }

    const int lane = threadIdx.x & 63;
    const int wid  = threadIdx.x >> 6;       // 0 = compute wave, 1 = store wave

    float S=0.f, E=0.f, I=0.f, R=0.f;
    if (wid == 0) {
        const int b = blockIdx.x * 64 + lane;
        S = S0[b]; E = E0[b]; I = I0[b]; R = R0[b];
    }

    // Store-wave addressing: lane l -> component (l>>4), trajectories
    // 4*(l&15)..+3 of this block. One dwordx4 = 4 x 256B segments.
    float* const obase = out + blockIdx.x * 64
                             + (lane >> 4) * B_TRAJ + (lane & 15) * 4;

    // One SEIR step, fma-fused: u = iD+ai = fma(btnD,P, sqrt(P)*wx), etc.
    // Sn=Sc-u; En=Ec+u-v; In=Ic+v-r; Rn=Rc+r. Same quantities as the
    // validated R12 form, regrouped (threshold margin ~200, abs diffs ulp).
    #define SEIR_STEP(w, dst)                                                  \
    {                                                                          \
        const float Sc = fmaxf(S, EPS);                                        \
        const float Ec = fmaxf(E, EPS);                                        \
        const float Ic = fmaxf(I, EPS);                                        \
        const float Rc = fmaxf(R, EPS);                                        \
        const float P  = Sc * Ic;                                              \
        const float u  = __builtin_fmaf(btnD, P,                               \
                              __builtin_amdgcn_sqrtf(P)  * (w).x);             \
        const float v  = __builtin_fmaf(sgD, Ec,                               \
                              __builtin_amdgcn_sqrtf(Ec) * (w).y);             \
        const float r  = __builtin_fmaf(gmD, Ic,                               \
                              __builtin_amdgcn_sqrtf(Ic) * (w).z);             \
        const float Sn = Sc - u;                                               \
        const float En = Ec + u - v;                                           \
        const float In = Ic + v - r;                                           \
        const float Rn = Rc + r;                                               \
        (dst)[0][lane] = Sn;                                                   \
        (dst)[1][lane] = En;                                                   \
        (dst)[2][lane] = In;                                                   \
        (dst)[3][lane] = Rn;                                                   \
        S = Sn; E = En; I = In; R = Rn;                                        \
    }

    // Compute wave: hoist the chunk's noise into registers (one batched
    // latency exposure), then run K LDS-read-free steps.
    #define FILL(c)                                                            \
    {                                                                          \
        const int s0 = (c) * K;                                                \
        float4 wv[K];                                                          \
        _Pragma("unroll")                                                      \
        for (int k = 0; k < K; ++k) wv[k] = wbuf[s0 + k];                      \
        float (*rw)[4][64] = ring[(c) & 1];                                    \
        _Pragma("unroll")                                                      \
        for (int k = 0; k < K; ++k) SEIR_STEP(wv[k], rw[k]);                   \
    }

    // Store wave: drain chunk c through register set v (20 b128 reads, then
    // 20 dwordx4 stores). Alternating v sets across chunks => compiler's WAR
    // wait is vmcnt(~K), keeping a full chunk of stores in flight always.
    #define STORE_CHUNK(c, v)                                                  \
    {                                                                          \
        const float4* rd = (const float4*)&ring[(c) & 1][0][0][0];             \
        float* o = obase + (size_t)((c) * K) * (4 * B_TRAJ);                   \
        _Pragma("unroll")                                                      \
        for (int k = 0; k < K; ++k) v[k] = rd[k * 64 + lane];                  \
        _Pragma("unroll")                                                      \
        for (int k = 0; k < K; ++k) {                                          \
            *(float4*)o = v[k];                                                \
            o += 4 * B_TRAJ;                                                   \
        }                                                                      \
    }

    float4 va[K], vb[K];                     // two in-flight store sets

    __syncthreads();                         // noise staged (once; drain ok)

    // ---- prologue: compute wave fills chunk 0 ----
    if (wid == 0) FILL(0);
    barrier_lds_only();

    // ---- pipeline, 2 chunks per iteration (NC even) ----
    for (int cc = 0; cc < NC; cc += 2) {
        if (wid == 0) { FILL(cc + 1); }
        else          { STORE_CHUNK(cc, va); }
        barrier_lds_only();
        if (wid == 0) { if (cc + 2 < NC) FILL(cc + 2); }
        else          { STORE_CHUNK(cc + 1, vb); }
        barrier_lds_only();
    }
    #undef SEIR_STEP
    #undef FILL
    #undef STORE_CHUNK
}

extern "C" void kernel_launch(void* const* d_in, const int* in_sizes, int n_in,
                              void* d_out, int out_size, void* d_ws, size_t ws_size,
                              hipStream_t stream) {
    const float*  beta  = (const float*)d_in[0];
    const float*  sigma = (const float*)d_in[1];
    const float*  gamma = (const float*)d_in[2];
    const float*  S0    = (const float*)d_in[3];
    const float*  E0    = (const float*)d_in[4];
    const float*  I0    = (const float*)d_in[5];
    const float*  R0    = (const float*)d_in[6];
    const float4* dW    = (const float4*)d_in[7];
    float* out = (float*)d_out;

    seir_sde_kernel<<<B_TRAJ / 64, 128, 0, stream>>>(
        beta, sigma, gamma, S0, E0, I0, R0, dW, out);
}

// Round 17
// 89.452 us; speedup vs baseline: 1.2517x; 1.2218x over previous
//
#include <hip/hip_runtime.h>

// SEIR SDE: B=32768 x 1000 steps -> out[step][4][B] f32 = 524 MB (write-bound).
// Best = R12 (94.2us): 512 blocks x {1 compute, 1 store} wave, K=20 SoA ring,
// per-step noise ds_read, va/vb double store reg-sets. Falsified: prefetch
// (R3), barrier drain (R8), compute-LDS removal (R11), noise hoist (R11,R16),
// K-slice store split (R13), XCD swizzle (R14), ILP2-single-wave (R15).
// Last unisolated lever: STORE SEGMENT WIDTH (R12 = 256B segments).
// R17 = R12 fill side (2 parallel ILP=1 compute waves/CU) + R15 store side
// (component-pair split store waves, 512B segments): block=256 = 2 compute
// waves (64 trajs each) + 2 store waves; grid=256 (1 block/CU via 96KB LDS).
// Per-CU byte rates identical to R12; only segment width changes.

constexpr int   B_TRAJ  = 32768;
constexpr int   NSTEPS  = 1000;
constexpr int   K       = 20;            // steps per chunk
constexpr int   NC      = NSTEPS / K;    // 50 chunks (even)
constexpr int   TPB     = 128;           // trajectories per block
constexpr float DT      = 0.01f;
constexpr float EPS     = 1e-6f;
constexpr float INV_N   = 1.0f / 10000.0f;

// Barrier without vmcnt drain: LDS ordering only; global stores stay in
// flight across chunk boundaries.
__device__ __forceinline__ void barrier_lds_only() {
    asm volatile("s_waitcnt lgkmcnt(0)" ::: "memory");
    __builtin_amdgcn_s_barrier();
    asm volatile("" ::: "memory");
}

__global__ __launch_bounds__(256) void seir_sde_kernel(
    const float* __restrict__ beta,
    const float* __restrict__ sigma,
    const float* __restrict__ gamma,
    const float* __restrict__ S0,
    const float* __restrict__ E0,
    const float* __restrict__ I0,
    const float* __restrict__ R0,
    const float4* __restrict__ dW,   // [NSTEPS] raw (w0,w1,w2,w3)
    float* __restrict__ out)         // [NSTEPS][4][B_TRAJ]
{
    __shared__ float4 wbuf[NSTEPS];          // pre-scaled noise, 16 KB
    __shared__ float  ring[2][K][4][TPB];    // SoA chunk ring, 80 KB
                                             // 96 KB total -> 1 block/CU

    // Folded constants (3 scalar loads, once, all threads).
    const float btnD = beta[0] * INV_N * DT; // (beta/N)*DT
    const float sgD  = sigma[0] * DT;        // sigma*DT
    const float gmD  = gamma[0] * DT;        // gamma*DT
    const float sbi  = __builtin_amdgcn_sqrtf(btnD);
    const float sbe  = __builtin_amdgcn_sqrtf(sgD);
    const float sbr  = __builtin_amdgcn_sqrtf(gmD);

    // Stage noise pre-multiplied: per-step diffusion becomes sqrt(P)*w.
    for (int i = threadIdx.x; i < NSTEPS; i += 256) {
        const float4 w = dW[i];
        wbuf[i] = make_float4(w.x * sbi, w.y * sbe, w.z * sbr, 0.0f);
    }

    const int lane = threadIdx.x & 63;
    const int wid  = threadIdx.x >> 6;       // 0,1 = compute; 2,3 = store

    // Compute wave cw owns trajs [block*128 + cw*64 + lane].
    const int cw = wid;                      // valid for wid<2
    const int t  = cw * 64 + lane;           // LDS traj index (compute)
    float S=0.f, E=0.f, I=0.f, R=0.f;
    if (wid < 2) {
        const int b = blockIdx.x * TPB + t;
        S = S0[b]; E = E0[b]; I = I0[b]; R = R0[b];
    }

    // Store wave sw handles component pair c0=2*sw, c0+1. Lanes 0-31 ->
    // comp c0, lanes 32-63 -> comp c0+1; each half = 512B contiguous segment.
    const int c0 = (wid - 2) * 2;            // valid for wid>=2
    float* const obase = out + blockIdx.x * TPB
                             + (c0 + (lane >> 5)) * B_TRAJ + (lane & 31) * 4;

    // One SEIR step, verbatim R12 (validated absmax 0.0): per-step wbuf read,
    // diffusion = sqrt(P)*w with sqrt(const*DT) folded into wbuf at staging.
    #define SEIR_STEP(w, dst)                                                  \
    {                                                                          \
        const float Sc = fmaxf(S, EPS);                                        \
        const float Ec = fmaxf(E, EPS);                                        \
        const float Ic = fmaxf(I, EPS);                                        \
        const float Rc = fmaxf(R, EPS);                                        \
        const float P  = Sc * Ic;                                              \
        const float iD = btnD * P;                                             \
        const float eD = sgD * Ec;                                             \
        const float rD = gmD * Ic;                                             \
        const float ai = __builtin_amdgcn_sqrtf(P)  * (w).x;                   \
        const float ae = __builtin_amdgcn_sqrtf(Ec) * (w).y;                   \
        const float ar = __builtin_amdgcn_sqrtf(Ic) * (w).z;                   \
        const float Sn = Sc - iD - ai;                                         \
        const float En = Ec + iD - eD + ai - ae;                               \
        const float In = Ic + eD - rD + ae - ar;                               \
        const float Rn = Rc + rD + ar;                                         \
        (dst)[0][t] = Sn;                                                      \
        (dst)[1][t] = En;                                                      \
        (dst)[2][t] = In;                                                      \
        (dst)[3][t] = Rn;                                                      \
        S = Sn; E = En; I = In; R = Rn;                                        \
    }

    // Compute waves: fill chunk c into ring[c&1] (each wave its 64 trajs).
    #define FILL(c)                                                            \
    {                                                                          \
        const int s0 = (c) * K;                                                \
        float (*rw)[4][TPB] = ring[(c) & 1];                                   \
        _Pragma("unroll")                                                      \
        for (int k = 0; k < K; ++k) {                                          \
            const float4 w = wbuf[s0 + k];                                     \
            SEIR_STEP(w, rw[k]);                                               \
        }                                                                      \
    }

    // Store wave: drain its comp-pair slice of chunk c via register set v.
    // Per step: 1KB contiguous ds_read_b128 + dwordx4 (2 x 512B segments).
    // Alternating v sets across chunks => counted-vmcnt WAR, full chunk-slice
    // of stores in flight permanently (R12 machinery).
    #define STORE_CHUNK(c, v)                                                  \
    {                                                                          \
        const float4* rd = (const float4*)&ring[(c) & 1][0][c0][0];            \
        float* o = obase + (size_t)((c) * K) * (4 * B_TRAJ);                   \
        _Pragma("unroll")                                                      \
        for (int k = 0; k < K; ++k) v[k] = rd[k * (TPB) + lane];               \
        _Pragma("unroll")                                                      \
        for (int k = 0; k < K; ++k) {                                          \
            *(float4*)o = v[k];                                                \
            o += 4 * B_TRAJ;                                                   \
        }                                                                      \
    }

    float4 va[K], vb[K];                     // two in-flight store sets

    __syncthreads();                         // noise staged (once; drain ok)

    // ---- prologue: compute waves fill chunk 0 ----
    if (wid < 2) FILL(0);
    barrier_lds_only();

    // ---- pipeline, 2 chunks per iteration (NC even) ----
    for (int cc = 0; cc < NC; cc += 2) {
        if (wid < 2) { FILL(cc + 1); }
        else         { STORE_CHUNK(cc, va); }
        barrier_lds_only();
        if (wid < 2) { if (cc + 2 < NC) FILL(cc + 2); }
        else         { STORE_CHUNK(cc + 1, vb); }
        barrier_lds_only();
    }
    #undef SEIR_STEP
    #undef FILL
    #undef STORE_CHUNK
}

extern "C" void kernel_launch(void* const* d_in, const int* in_sizes, int n_in,
                              void* d_out, int out_size, void* d_ws, size_t ws_size,
                              hipStream_t stream) {
    const float*  beta  = (const float*)d_in[0];
    const float*  sigma = (const float*)d_in[1];
    const float*  gamma = (const float*)d_in[2];
    const float*  S0    = (const float*)d_in[3];
    const float*  E0    = (const float*)d_in[4];
    const float*  I0    = (const float*)d_in[5];
    const float*  R0    = (const float*)d_in[6];
    const float4* dW    = (const float4*)d_in[7];
    float* out = (float*)d_out;

    seir_sde_kernel<<<B_TRAJ / TPB, 256, 0, stream>>>(
        beta, sigma, gamma, S0, E0, I0, R0, dW, out);
}